// Round 1
// baseline (378.378 us; speedup 1.0000x reference)
//
#include <hip/hip_runtime.h>
#include <hip/hip_bf16.h>
#include <math.h>

// Problem: B=8, N=16384 (H=W=128), C=64, heads=1, d=64, SR=8 -> Nk=256.
// Pipeline: q = x@Wq+bq ; xr = LN(conv_s8(x)) ; k,v = xr@Wkv+bkv ;
//           out = softmax(q k^T / 8) v ; y = out@Wp + bp
// fp32 everywhere this round (correct baseline; CDNA4 has no fp32 MFMA).

#define B 8
#define N 16384
#define C 64
#define NK 256
#define HW 128

// ---------------------------------------------------------------------------
// Kernel T: transpose sr_w [o][c][ki][kj] (= [o][e], e = c*64+ki*8+kj)
//           into Wt [e][o] so conv weight staging is coalesced.
__global__ __launch_bounds__(256) void transpose_w(const float* __restrict__ sr_w,
                                                   float* __restrict__ Wt) {
  int idx = blockIdx.x * 256 + threadIdx.x;   // 262144 total
  int o = idx >> 12;         // [0,64)
  int e = idx & 4095;        // [0,4096)
  // coalesced read (idx is linear over sr_w), scattered write (L2 absorbs)
  Wt[e * 64 + o] = sr_w[idx];
}

// ---------------------------------------------------------------------------
// Kernel A: conv(k=8,s=8) + bias + LayerNorm + KV projection.
// Grid: 256 blocks = b(8) x pg(32); each block does 8 patches, all 64 outputs.
// conv as GEMM: xr[p][o] = sum_e A[p][e] * Wt[e][o], e-chunks of 256 in LDS.
__global__ __launch_bounds__(256) void conv_ln_kv(
    const float* __restrict__ x, const float* __restrict__ Wt,
    const float* __restrict__ sr_b, const float* __restrict__ ln_g,
    const float* __restrict__ ln_b, const float* __restrict__ Wkv,
    const float* __restrict__ bkv, float* __restrict__ Kws,
    float* __restrict__ Vws) {
  __shared__ float As[8 * 260];   // patch tile, padded stride 260 (bank-safe)
  __shared__ float Ws[256 * 64];  // weight chunk [ec][o]
  __shared__ float red[128 * 4];  // half-sum reduction
  __shared__ float ns[8 * 64];    // conv result -> normalized rows

  const int t = threadIdx.x;
  const int b = blockIdx.x >> 5;
  const int pg = blockIdx.x & 31;
  const int oq = t & 15;          // output quad
  const int pp = (t >> 4) & 7;    // patch
  const int half = t >> 7;        // ec-range half

  float acc0 = 0.f, acc1 = 0.f, acc2 = 0.f, acc3 = 0.f;
  const float4* f4Wt = reinterpret_cast<const float4*>(Wt);
  float4* f4Ws = reinterpret_cast<float4*>(Ws);

  for (int ch = 0; ch < 16; ch++) {
    const int cb4 = ch * 4;  // channel base
    __syncthreads();         // previous chunk fully consumed
    // stage patch data: As[p][cc*64 + r] = x[b][pos(p,r)][cb4+cc]
#pragma unroll
    for (int u = 0; u < 2; u++) {
      int n2 = t + u * 256;            // [0,512)
      int p = n2 >> 6, r = n2 & 63;
      int P = pg * 8 + p;
      int pos = ((P >> 4) * 8 + (r >> 3)) * HW + (P & 15) * 8 + (r & 7);
      float4 xv = *reinterpret_cast<const float4*>(
          x + ((size_t)b * N + pos) * C + cb4);
      As[p * 260 + 0 * 64 + r] = xv.x;
      As[p * 260 + 1 * 64 + r] = xv.y;
      As[p * 260 + 2 * 64 + r] = xv.z;
      As[p * 260 + 3 * 64 + r] = xv.w;
    }
    // stage weight chunk: Ws[ec][o] <- Wt[cb4*64 + ec][o]  (coalesced f4)
#pragma unroll
    for (int u = 0; u < 16; u++) {
      int ii = t + u * 256;            // [0,4096) float4s
      f4Ws[ii] = f4Wt[cb4 * 1024 + ii];
    }
    __syncthreads();
    const int ecbase = half * 128;
#pragma unroll 8
    for (int ec4 = 0; ec4 < 32; ec4++) {
      int ec = ecbase + ec4 * 4;
      float4 a4 = *reinterpret_cast<const float4*>(&As[pp * 260 + ec]);
      float4 w0 = f4Ws[(ec + 0) * 16 + oq];
      float4 w1 = f4Ws[(ec + 1) * 16 + oq];
      float4 w2 = f4Ws[(ec + 2) * 16 + oq];
      float4 w3 = f4Ws[(ec + 3) * 16 + oq];
      acc0 += a4.x * w0.x + a4.y * w1.x + a4.z * w2.x + a4.w * w3.x;
      acc1 += a4.x * w0.y + a4.y * w1.y + a4.z * w2.y + a4.w * w3.y;
      acc2 += a4.x * w0.z + a4.y * w1.z + a4.z * w2.z + a4.w * w3.z;
      acc3 += a4.x * w0.w + a4.y * w1.w + a4.z * w2.w + a4.w * w3.w;
    }
  }
  __syncthreads();
  // combine the two ec-halves
  if (half == 1) {
    red[(t - 128) * 4 + 0] = acc0;
    red[(t - 128) * 4 + 1] = acc1;
    red[(t - 128) * 4 + 2] = acc2;
    red[(t - 128) * 4 + 3] = acc3;
  }
  __syncthreads();
  if (half == 0) {
    acc0 += red[t * 4 + 0];
    acc1 += red[t * 4 + 1];
    acc2 += red[t * 4 + 2];
    acc3 += red[t * 4 + 3];
    float4 bias = reinterpret_cast<const float4*>(sr_b)[oq];
    float4 r4 = make_float4(acc0 + bias.x, acc1 + bias.y, acc2 + bias.z,
                            acc3 + bias.w);
    *reinterpret_cast<float4*>(&ns[pp * 64 + oq * 4]) = r4;
  }
  __syncthreads();
  // LayerNorm: wave w handles rows {w, w+4}; lane = channel
  {
    const int lane = t & 63;
    const int w = t >> 6;
    float g = ln_g[lane], bb = ln_b[lane];
#pragma unroll
    for (int rr = 0; rr < 2; rr++) {
      int p = w + rr * 4;
      float v = ns[p * 64 + lane];
      float s = v, s2 = v * v;
#pragma unroll
      for (int mask = 1; mask < 64; mask <<= 1) {
        s += __shfl_xor(s, mask, 64);
        s2 += __shfl_xor(s2, mask, 64);
      }
      float mu = s * (1.f / 64.f);
      float var = s2 * (1.f / 64.f) - mu * mu;
      float nv = (v - mu) * rsqrtf(var + 1e-5f) * g + bb;
      ns[p * 64 + lane] = nv;  // lane writes only its own element
    }
  }
  __syncthreads();
  // KV projection: thread = (j in [0,128), rr0 in {0,1}) -> 4 rows each
  {
    const int j = t & 127;
    const int rr0 = t >> 7;
    float bj = bkv[j];
    float a0 = bj, a1 = bj, a2 = bj, a3 = bj;
#pragma unroll 16
    for (int c = 0; c < 64; c++) {
      float wv = Wkv[c * 128 + j];
      a0 += ns[(rr0 + 0) * 64 + c] * wv;
      a1 += ns[(rr0 + 2) * 64 + c] * wv;
      a2 += ns[(rr0 + 4) * 64 + c] * wv;
      a3 += ns[(rr0 + 6) * 64 + c] * wv;
    }
    float* dst = (j < 64) ? Kws : Vws;
    int jj = j & 63;
    size_t Pb = (size_t)b * NK + pg * 8;
    dst[(Pb + rr0 + 0) * 64 + jj] = a0;
    dst[(Pb + rr0 + 2) * 64 + jj] = a1;
    dst[(Pb + rr0 + 4) * 64 + jj] = a2;
    dst[(Pb + rr0 + 6) * 64 + jj] = a3;
  }
}

// ---------------------------------------------------------------------------
// Kernel B: fused q-proj + flash attention (Nk=256, 4 tiles of 64 in LDS)
//           + output projection. One thread per sequence row.
__global__ __launch_bounds__(256, 2) void attn_fused(
    const float* __restrict__ x, const float* __restrict__ Wq,
    const float* __restrict__ bq, const float* __restrict__ Wp,
    const float* __restrict__ bp, const float* __restrict__ Kws,
    const float* __restrict__ Vws, float* __restrict__ outp) {
  __shared__ float Wqs[4096];
  __shared__ float Wps[4096];
  __shared__ float Ks[4096];   // 64 x 64 K tile
  __shared__ float Vs[4096];   // 64 x 64 V tile

  const int t = threadIdx.x;
  const int b = blockIdx.x >> 6;
  const int rb = blockIdx.x & 63;
  const int row = rb * 256 + t;

  float4* f4Wqs = reinterpret_cast<float4*>(Wqs);
  float4* f4Wps = reinterpret_cast<float4*>(Wps);
#pragma unroll
  for (int u = 0; u < 4; u++) {
    f4Wqs[t + u * 256] = reinterpret_cast<const float4*>(Wq)[t + u * 256];
    f4Wps[t + u * 256] = reinterpret_cast<const float4*>(Wp)[t + u * 256];
  }
  __syncthreads();

  // q = bq + x_row @ Wq   (stream x, keep q[64] in regs)
  float q[64];
#pragma unroll
  for (int i = 0; i < 16; i++) {
    float4 bv = reinterpret_cast<const float4*>(bq)[i];
    q[4 * i + 0] = bv.x; q[4 * i + 1] = bv.y;
    q[4 * i + 2] = bv.z; q[4 * i + 3] = bv.w;
  }
  {
    const float4* xr4 =
        reinterpret_cast<const float4*>(x + ((size_t)b * N + row) * C);
#pragma unroll
    for (int i = 0; i < 16; i++) {
      float4 xv = xr4[i];
      float xc[4] = {xv.x, xv.y, xv.z, xv.w};
#pragma unroll
      for (int k = 0; k < 4; k++) {
        int c = 4 * i + k;
#pragma unroll
        for (int j4 = 0; j4 < 16; j4++) {
          float4 w = f4Wqs[c * 16 + j4];
          q[4 * j4 + 0] += xc[k] * w.x;
          q[4 * j4 + 1] += xc[k] * w.y;
          q[4 * j4 + 2] += xc[k] * w.z;
          q[4 * j4 + 3] += xc[k] * w.w;
        }
      }
    }
  }

  // online softmax over 256 keys, deferred-max (THR=8): rescale ~once/thread
  float m = -INFINITY, l = 0.f;
  float acc[64];
#pragma unroll
  for (int j = 0; j < 64; j++) acc[j] = 0.f;

  const float4* f4K = reinterpret_cast<const float4*>(Kws);
  const float4* f4V = reinterpret_cast<const float4*>(Vws);
  float4* f4Ks = reinterpret_cast<float4*>(Ks);
  float4* f4Vs = reinterpret_cast<float4*>(Vs);

  for (int tile = 0; tile < 4; tile++) {
    __syncthreads();
#pragma unroll
    for (int u = 0; u < 4; u++) {
      int ii = t + u * 256;
      f4Ks[ii] = f4K[b * 4096 + tile * 1024 + ii];
      f4Vs[ii] = f4V[b * 4096 + tile * 1024 + ii];
    }
    __syncthreads();
    for (int kk = 0; kk < 64; kk++) {
      float s0 = 0.f, s1 = 0.f, s2 = 0.f, s3 = 0.f;
#pragma unroll
      for (int c4 = 0; c4 < 16; c4 += 4) {
        float4 k0 = f4Ks[kk * 16 + c4 + 0];
        float4 k1 = f4Ks[kk * 16 + c4 + 1];
        float4 k2 = f4Ks[kk * 16 + c4 + 2];
        float4 k3 = f4Ks[kk * 16 + c4 + 3];
        s0 += q[4 * c4 + 0] * k0.x + q[4 * c4 + 1] * k0.y +
              q[4 * c4 + 2] * k0.z + q[4 * c4 + 3] * k0.w;
        s1 += q[4 * c4 + 4] * k1.x + q[4 * c4 + 5] * k1.y +
              q[4 * c4 + 6] * k1.z + q[4 * c4 + 7] * k1.w;
        s2 += q[4 * c4 + 8] * k2.x + q[4 * c4 + 9] * k2.y +
              q[4 * c4 + 10] * k2.z + q[4 * c4 + 11] * k2.w;
        s3 += q[4 * c4 + 12] * k3.x + q[4 * c4 + 13] * k3.y +
              q[4 * c4 + 14] * k3.z + q[4 * c4 + 15] * k3.w;
      }
      float s = ((s0 + s1) + (s2 + s3)) * 0.125f;
      float p;
      if (s > m + 8.f) {           // rare after first key (defer-max)
        float f = __expf(m - s);   // exp(-inf)=0 on first hit
        l *= f;
#pragma unroll
        for (int j = 0; j < 64; j++) acc[j] *= f;
        m = s;
        p = 1.f;
      } else {
        p = __expf(s - m);
      }
      l += p;
#pragma unroll
      for (int c4 = 0; c4 < 16; c4++) {
        float4 v4 = f4Vs[kk * 16 + c4];
        acc[4 * c4 + 0] += p * v4.x;
        acc[4 * c4 + 1] += p * v4.y;
        acc[4 * c4 + 2] += p * v4.z;
        acc[4 * c4 + 3] += p * v4.w;
      }
    }
  }
  float linv = 1.f / l;
#pragma unroll
  for (int j = 0; j < 64; j++) acc[j] *= linv;

  // y = bp + acc @ Wp
  float y[64];
#pragma unroll
  for (int i = 0; i < 16; i++) {
    float4 bv = reinterpret_cast<const float4*>(bp)[i];
    y[4 * i + 0] = bv.x; y[4 * i + 1] = bv.y;
    y[4 * i + 2] = bv.z; y[4 * i + 3] = bv.w;
  }
#pragma unroll
  for (int c = 0; c < 64; c++) {
    float oc = acc[c];
#pragma unroll
    for (int j4 = 0; j4 < 16; j4++) {
      float4 w = f4Wps[c * 16 + j4];
      y[4 * j4 + 0] += oc * w.x;
      y[4 * j4 + 1] += oc * w.y;
      y[4 * j4 + 2] += oc * w.z;
      y[4 * j4 + 3] += oc * w.w;
    }
  }
  float4* o4 = reinterpret_cast<float4*>(outp + ((size_t)b * N + row) * C);
#pragma unroll
  for (int j4 = 0; j4 < 16; j4++) {
    o4[j4] = make_float4(y[4 * j4 + 0], y[4 * j4 + 1], y[4 * j4 + 2],
                         y[4 * j4 + 3]);
  }
}

// ---------------------------------------------------------------------------
extern "C" void kernel_launch(void* const* d_in, const int* in_sizes, int n_in,
                              void* d_out, int out_size, void* d_ws,
                              size_t ws_size, hipStream_t stream) {
  const float* x    = (const float*)d_in[0];
  // d_in[1]=H, d_in[2]=W (ints, fixed 128 here)
  const float* Wq   = (const float*)d_in[3];
  const float* bq   = (const float*)d_in[4];
  const float* Wkv  = (const float*)d_in[5];
  const float* bkv  = (const float*)d_in[6];
  const float* sr_w = (const float*)d_in[7];
  const float* sr_b = (const float*)d_in[8];
  const float* ln_g = (const float*)d_in[9];
  const float* ln_b = (const float*)d_in[10];
  const float* Wp   = (const float*)d_in[11];
  const float* bp   = (const float*)d_in[12];
  float* outp = (float*)d_out;

  float* Wt  = (float*)d_ws;          // 262144 floats (1 MB)
  float* Kws = Wt + 262144;           // 131072 floats (512 KB)
  float* Vws = Kws + 131072;          // 131072 floats (512 KB)

  transpose_w<<<1024, 256, 0, stream>>>(sr_w, Wt);
  conv_ln_kv<<<256, 256, 0, stream>>>(x, Wt, sr_b, ln_g, ln_b, Wkv, bkv, Kws,
                                      Vws);
  attn_fused<<<512, 256, 0, stream>>>(x, Wq, bq, Wp, bp, Kws, Vws, outp);
}

// Round 3
// 133.985 us; speedup vs baseline: 2.8240x; 2.8240x over previous
//
#include <hip/hip_runtime.h>
#include <hip/hip_bf16.h>
#include <math.h>

// B=8, N=16384 (H=W=128), C=64, heads=1, d=64, SR=8 -> Nk=256.
// Algebra: S = X @ (Wq K^T)/8 + bq.K^T/8 ; P = softmax(S) ; out = P @ (V Wp) + bp
// prep builds MT=(Wq K^T)*0.125*log2e (bf16, fragment-linear), sb, VpT=(V Wp)^T.
// attn kernel: per-wave 32 queries, MFMA 32x32x16 bf16 (swapped operands:
// S^T = MT . X^T so each lane owns one query row; softmax lane-local).
// R3 fix: softmax cross-half reductions via __shfl_xor (the R2 inline-asm
// permlane on two provably-equal "+v" operands could alias to ONE register ->
// self-swap -> lane loses its own partial max/sum).

#define B 8
#define N 16384
#define C 64
#define NK 256
#define HW 128

typedef unsigned short ushort_t;
typedef unsigned int uint_t;
typedef __attribute__((ext_vector_type(8))) short short8v;
typedef __attribute__((ext_vector_type(16))) float f32x16;

static __device__ inline ushort_t f2bf(float f) {
  __hip_bfloat16 h = __float2bfloat16(f);
  return *reinterpret_cast<ushort_t*>(&h);
}
static __device__ inline uint_t pk2(float a, float b) {
  return (uint_t)f2bf(a) | ((uint_t)f2bf(b) << 16);
}
static __device__ inline short8v mk8(uint_t a, uint_t b, uint_t c, uint_t d) {
  union { int4 i; short8v s; } u;
  u.i = make_int4((int)a, (int)b, (int)c, (int)d);
  return u.s;
}
static __device__ inline float max16(const f32x16 v) {
  float a = fmaxf(fmaxf(fmaxf(v[0], v[1]), fmaxf(v[2], v[3])),
                  fmaxf(fmaxf(v[4], v[5]), fmaxf(v[6], v[7])));
  float b = fmaxf(fmaxf(fmaxf(v[8], v[9]), fmaxf(v[10], v[11])),
                  fmaxf(fmaxf(v[12], v[13]), fmaxf(v[14], v[15])));
  return fmaxf(a, b);
}
static __device__ inline float sum16(const f32x16 v) {
  float a = ((v[0] + v[1]) + (v[2] + v[3])) + ((v[4] + v[5]) + (v[6] + v[7]));
  float b = ((v[8] + v[9]) + (v[10] + v[11])) + ((v[12] + v[13]) + (v[14] + v[15]));
  return a + b;
}

// ---------------------------------------------------------------------------
// Kernel T: transpose sr_w [o][e] -> Wt [e][o] (conv weight staging coalesce)
__global__ __launch_bounds__(256) void transpose_w(const float* __restrict__ sr_w,
                                                   float* __restrict__ Wt) {
  int idx = blockIdx.x * 256 + threadIdx.x;
  int o = idx >> 12;
  int e = idx & 4095;
  Wt[e * 64 + o] = sr_w[idx];
}

// ---------------------------------------------------------------------------
// Kernel A: conv(k=8,s=8) + bias + LayerNorm + KV projection (fp32)
__global__ __launch_bounds__(256) void conv_ln_kv(
    const float* __restrict__ x, const float* __restrict__ Wt,
    const float* __restrict__ sr_b, const float* __restrict__ ln_g,
    const float* __restrict__ ln_b, const float* __restrict__ Wkv,
    const float* __restrict__ bkv, float* __restrict__ Kws,
    float* __restrict__ Vws) {
  __shared__ float As[8 * 260];
  __shared__ float Ws[256 * 64];
  __shared__ float red[128 * 4];
  __shared__ float ns[8 * 64];

  const int t = threadIdx.x;
  const int b = blockIdx.x >> 5;
  const int pg = blockIdx.x & 31;
  const int oq = t & 15;
  const int pp = (t >> 4) & 7;
  const int half = t >> 7;

  float acc0 = 0.f, acc1 = 0.f, acc2 = 0.f, acc3 = 0.f;
  const float4* f4Wt = reinterpret_cast<const float4*>(Wt);
  float4* f4Ws = reinterpret_cast<float4*>(Ws);

  for (int ch = 0; ch < 16; ch++) {
    const int cb4 = ch * 4;
    __syncthreads();
#pragma unroll
    for (int u = 0; u < 2; u++) {
      int n2 = t + u * 256;
      int p = n2 >> 6, r = n2 & 63;
      int P = pg * 8 + p;
      int pos = ((P >> 4) * 8 + (r >> 3)) * HW + (P & 15) * 8 + (r & 7);
      float4 xv = *reinterpret_cast<const float4*>(
          x + ((size_t)b * N + pos) * C + cb4);
      As[p * 260 + 0 * 64 + r] = xv.x;
      As[p * 260 + 1 * 64 + r] = xv.y;
      As[p * 260 + 2 * 64 + r] = xv.z;
      As[p * 260 + 3 * 64 + r] = xv.w;
    }
#pragma unroll
    for (int u = 0; u < 16; u++) {
      int ii = t + u * 256;
      f4Ws[ii] = f4Wt[cb4 * 1024 + ii];
    }
    __syncthreads();
    const int ecbase = half * 128;
#pragma unroll 8
    for (int ec4 = 0; ec4 < 32; ec4++) {
      int ec = ecbase + ec4 * 4;
      float4 a4 = *reinterpret_cast<const float4*>(&As[pp * 260 + ec]);
      float4 w0 = f4Ws[(ec + 0) * 16 + oq];
      float4 w1 = f4Ws[(ec + 1) * 16 + oq];
      float4 w2 = f4Ws[(ec + 2) * 16 + oq];
      float4 w3 = f4Ws[(ec + 3) * 16 + oq];
      acc0 += a4.x * w0.x + a4.y * w1.x + a4.z * w2.x + a4.w * w3.x;
      acc1 += a4.x * w0.y + a4.y * w1.y + a4.z * w2.y + a4.w * w3.y;
      acc2 += a4.x * w0.z + a4.y * w1.z + a4.z * w2.z + a4.w * w3.z;
      acc3 += a4.x * w0.w + a4.y * w1.w + a4.z * w2.w + a4.w * w3.w;
    }
  }
  __syncthreads();
  if (half == 1) {
    red[(t - 128) * 4 + 0] = acc0;
    red[(t - 128) * 4 + 1] = acc1;
    red[(t - 128) * 4 + 2] = acc2;
    red[(t - 128) * 4 + 3] = acc3;
  }
  __syncthreads();
  if (half == 0) {
    acc0 += red[t * 4 + 0];
    acc1 += red[t * 4 + 1];
    acc2 += red[t * 4 + 2];
    acc3 += red[t * 4 + 3];
    float4 bias = reinterpret_cast<const float4*>(sr_b)[oq];
    float4 r4 = make_float4(acc0 + bias.x, acc1 + bias.y, acc2 + bias.z,
                            acc3 + bias.w);
    *reinterpret_cast<float4*>(&ns[pp * 64 + oq * 4]) = r4;
  }
  __syncthreads();
  {
    const int lane = t & 63;
    const int w = t >> 6;
    float g = ln_g[lane], bb = ln_b[lane];
#pragma unroll
    for (int rr = 0; rr < 2; rr++) {
      int p = w + rr * 4;
      float v = ns[p * 64 + lane];
      float s = v, s2 = v * v;
#pragma unroll
      for (int mask = 1; mask < 64; mask <<= 1) {
        s += __shfl_xor(s, mask, 64);
        s2 += __shfl_xor(s2, mask, 64);
      }
      float mu = s * (1.f / 64.f);
      float var = s2 * (1.f / 64.f) - mu * mu;
      float nv = (v - mu) * rsqrtf(var + 1e-5f) * g + bb;
      ns[p * 64 + lane] = nv;
    }
  }
  __syncthreads();
  {
    const int j = t & 127;
    const int rr0 = t >> 7;
    float bj = bkv[j];
    float a0 = bj, a1 = bj, a2 = bj, a3 = bj;
#pragma unroll 16
    for (int c = 0; c < 64; c++) {
      float wv = Wkv[c * 128 + j];
      a0 += ns[(rr0 + 0) * 64 + c] * wv;
      a1 += ns[(rr0 + 2) * 64 + c] * wv;
      a2 += ns[(rr0 + 4) * 64 + c] * wv;
      a3 += ns[(rr0 + 6) * 64 + c] * wv;
    }
    float* dst = (j < 64) ? Kws : Vws;
    int jj = j & 63;
    size_t Pb = (size_t)b * NK + pg * 8;
    dst[(Pb + rr0 + 0) * 64 + jj] = a0;
    dst[(Pb + rr0 + 2) * 64 + jj] = a1;
    dst[(Pb + rr0 + 4) * 64 + jj] = a2;
    dst[(Pb + rr0 + 6) * 64 + jj] = a3;
  }
}

// ---------------------------------------------------------------------------
// Kernel P: per-batch operand prep.
//   MT[j][c]  = (sum_d Wq[c][d] K[j][d]) * 0.125 * log2(e)   (bf16 frag-linear)
//   sb[j]     = (sum_d bq[d]   K[j][d]) * 0.125 * log2(e)    (bf16)
//   VpT[c][j] = (sum_d V[j][d] Wp[d][c])                     (bf16 frag-linear)
// Frag-linear for mfma_f32_32x32x16_bf16 A-operand (row=l&31, k=(l>>5)*8+e):
// MTf chunk(kt,ks) -> ushort off (kt*4+ks)*512 + l*8 + e,
// l = ((c>>3)&1)*32 | (j&31), e=c&7.  VpTf chunk(ct,ks): l=((j>>3)&1)*32|(c&31).
__global__ __launch_bounds__(256) void prep(
    const float* __restrict__ Kws, const float* __restrict__ Vws,
    const float* __restrict__ Wq, const float* __restrict__ bq,
    const float* __restrict__ Wp, ushort_t* __restrict__ MTf,
    ushort_t* __restrict__ VpTf, ushort_t* __restrict__ sbf) {
  __shared__ float sA[64 * 65];      // padded weight tile
  __shared__ float sBv[64 * 257];    // padded data tile
  const int t = threadIdx.x;
  const int b = blockIdx.x >> 3;
  const int p = blockIdx.x & 7;
  const float SC = 0.125f * 1.4426950408889634f;

  if (p < 4) {
    // ---- MT quarter: rows j in [p*64, p*64+64) ----
#pragma unroll
    for (int i = 0; i < 16; ++i) {
      int o = t + 256 * i;
      sA[(o & 63) * 65 + (o >> 6)] = Wq[o];   // sA[d][c] = Wq[c][d]
    }
    {
      const float4* k4 =
          reinterpret_cast<const float4*>(Kws + ((size_t)b * NK + p * 64) * 64);
      float4* b4 = reinterpret_cast<float4*>(sBv);
#pragma unroll
      for (int i = 0; i < 4; ++i) b4[t + 256 * i] = k4[t + 256 * i];
    }
    __syncthreads();
    const int c = t & 63;
    const int jbase = t >> 6;
    float wcol[64];
#pragma unroll
    for (int d = 0; d < 64; ++d) wcol[d] = sA[d * 65 + c];
    const int ks = c >> 4;
    const int lpart = ((c >> 3) & 1) * 32;
    const int e = c & 7;
#pragma unroll 4
    for (int u = 0; u < 16; ++u) {
      int jl = jbase + 4 * u;
      float s = 0.f;
#pragma unroll
      for (int d = 0; d < 64; ++d) s += sBv[jl * 64 + d] * wcol[d];
      int j = p * 64 + jl;
      int kt = j >> 5;
      int l = lpart + (j & 31);
      MTf[(size_t)b * 16384 + (kt * 4 + ks) * 512 + l * 8 + e] = f2bf(s * SC);
    }
    if (t < 64) {
      float s = 0.f;
      for (int d = 0; d < 64; ++d) s += bq[d] * sBv[t * 64 + d];
      sbf[b * NK + p * 64 + t] = f2bf(s * SC);
    }
  } else {
    // ---- VpT quarter: c in [pc*16, pc*16+16) ----
    const int pc = p - 4;
#pragma unroll
    for (int i = 0; i < 16; ++i) {
      int o = t + 256 * i;                 // o = d*64 + c
      sA[(o >> 6) * 65 + (o & 63)] = Wp[o];  // sA[d][c] = Wp[d][c]
    }
    {
      const float* Vb = Vws + (size_t)b * NK * 64;
#pragma unroll
      for (int i = 0; i < 64; ++i) {
        int o = t + 256 * i;               // o = j*64 + d
        sBv[(o & 63) * 257 + (o >> 6)] = Vb[o];  // sBv[d][j] = V[j][d]
      }
    }
    __syncthreads();
    const int j = t;  // 0..255
    float vrow[64];
#pragma unroll
    for (int d = 0; d < 64; ++d) vrow[d] = sBv[d * 257 + j];
    const int ks = j >> 4;
    const int lpart = ((j >> 3) & 1) * 32;
    const int e = j & 7;
#pragma unroll 4
    for (int u = 0; u < 16; ++u) {
      int c = pc * 16 + u;
      float s = 0.f;
#pragma unroll
      for (int d = 0; d < 64; ++d) s += vrow[d] * sA[d * 65 + c];
      int ct = c >> 5;
      int l = lpart + (c & 31);
      VpTf[(size_t)b * 16384 + (ct * 16 + ks) * 512 + l * 8 + e] = f2bf(s);
    }
  }
}

// ---------------------------------------------------------------------------
// Kernel B: MFMA attention. 512 blocks x 256 thr; block = (b, 256 rows).
// Wave handles 2 tiles of 32 rows. Per tile: S^T = MT.X^T (+bias k-step),
// lane-local softmax (log2 domain), P repack via v_permlane32_swap, out^T =
// VpT.P^T, epilogue *1/l + bp.
__global__ __launch_bounds__(256, 2) void attn_mfma(
    const float* __restrict__ x, const ushort_t* __restrict__ MTf,
    const ushort_t* __restrict__ VpTf, const ushort_t* __restrict__ sbf,
    const float* __restrict__ bp, float* __restrict__ outp) {
  __shared__ ushort_t sMT[16384];
  __shared__ ushort_t sVT[16384];
  __shared__ ushort_t sSB[256];

  const int t = threadIdx.x;
  const int b = blockIdx.x >> 6;
  const int rb = blockIdx.x & 63;
  const int wave = t >> 6;
  const int lane = t & 63;
  const int lo5 = lane & 31;
  const int hi = lane >> 5;

  {
    const uint4* gm = reinterpret_cast<const uint4*>(MTf + (size_t)b * 16384);
    const uint4* gv = reinterpret_cast<const uint4*>(VpTf + (size_t)b * 16384);
    uint4* dm = reinterpret_cast<uint4*>(sMT);
    uint4* dv = reinterpret_cast<uint4*>(sVT);
#pragma unroll
    for (int i = 0; i < 8; ++i) {
      dm[t + i * 256] = gm[t + i * 256];
      dv[t + i * 256] = gv[t + i * 256];
    }
    if (t < 32)
      reinterpret_cast<uint4*>(sSB)[t] =
          reinterpret_cast<const uint4*>(sbf + b * NK)[t];
  }
  __syncthreads();

  for (int t2 = 0; t2 < 2; ++t2) {
    const int row = rb * 256 + wave * 64 + t2 * 32 + lo5;
    const float* xrow = x + ((size_t)b * N + row) * 64;
    const float4* xp = reinterpret_cast<const float4*>(xrow);

    // X B-fragments (col=q=lane&31, k=c=ks*16+hi*8+e)
    short8v bx[4];
#pragma unroll
    for (int ks = 0; ks < 4; ++ks) {
      float4 f0 = xp[ks * 4 + hi * 2 + 0];
      float4 f1 = xp[ks * 4 + hi * 2 + 1];
      bx[ks] = mk8(pk2(f0.x, f0.y), pk2(f0.z, f0.w), pk2(f1.x, f1.y),
                   pk2(f1.z, f1.w));
    }

    // S^T accumulate: acc[kt] = 32 keys x 32 queries tile
    f32x16 acc[8];
#pragma unroll
    for (int kt = 0; kt < 8; ++kt)
#pragma unroll
      for (int r = 0; r < 16; ++r) acc[kt][r] = 0.f;

#pragma unroll
    for (int kt = 0; kt < 8; ++kt) {
#pragma unroll
      for (int ks = 0; ks < 4; ++ks) {
        const short8v a =
            *reinterpret_cast<const short8v*>(&sMT[(kt * 4 + ks) * 512 + lane * 8]);
        acc[kt] = __builtin_amdgcn_mfma_f32_32x32x16_bf16(a, bx[ks], acc[kt], 0, 0, 0);
      }
      // bias k-step: adds sb[key] to every query column
      ushort_t sv = sSB[kt * 32 + lo5];
      short8v a5 = mk8(hi ? 0u : (uint_t)sv, 0u, 0u, 0u);
      short8v b5 = mk8(hi ? 0u : 0x3F80u, 0u, 0u, 0u);
      acc[kt] = __builtin_amdgcn_mfma_f32_32x32x16_bf16(a5, b5, acc[kt], 0, 0, 0);
    }

    // lane-local softmax over 128 keys + cross-half (partner lane^32)
    float mx = max16(acc[0]);
#pragma unroll
    for (int kt = 1; kt < 8; ++kt) mx = fmaxf(mx, max16(acc[kt]));
    mx = fmaxf(mx, __shfl_xor(mx, 32, 64));   // safe cross-half max
    float sum = 0.f;
#pragma unroll
    for (int kt = 0; kt < 8; ++kt) {
#pragma unroll
      for (int r = 0; r < 16; ++r) acc[kt][r] = exp2f(acc[kt][r] - mx);
      sum += sum16(acc[kt]);
    }
    sum += __shfl_xor(sum, 32, 64);           // safe cross-half sum
    const float linv = 1.f / sum;

    // PV: out^T = VpT . P^T
    f32x16 o[2];
#pragma unroll
    for (int ct = 0; ct < 2; ++ct)
#pragma unroll
      for (int r = 0; r < 16; ++r) o[ct][r] = 0.f;

#pragma unroll
    for (int ks = 0; ks < 16; ++ks) {
      const int kt = ks >> 1;
      const int m0 = (ks & 1) * 2;
      uint_t Aw = pk2(acc[kt][4 * m0 + 0], acc[kt][4 * m0 + 1]);
      uint_t Bw = pk2(acc[kt][4 * m0 + 2], acc[kt][4 * m0 + 3]);
      uint_t Cw = pk2(acc[kt][4 * m0 + 4], acc[kt][4 * m0 + 5]);
      uint_t Dw = pk2(acc[kt][4 * m0 + 6], acc[kt][4 * m0 + 7]);
      // vdst.hi32 <-> vsrc.lo32 (Aw/Cw, Bw/Dw are distinct values -> distinct
      // regs; the e0..e7 key order after the swap matches B-frag k=hi*8+e)
      asm volatile("v_permlane32_swap_b32 %0, %1" : "+v"(Aw), "+v"(Cw));
      asm volatile("v_permlane32_swap_b32 %0, %1" : "+v"(Bw), "+v"(Dw));
      const short8v pb = mk8(Aw, Bw, Cw, Dw);
#pragma unroll
      for (int ct = 0; ct < 2; ++ct) {
        const short8v va =
            *reinterpret_cast<const short8v*>(&sVT[(ct * 16 + ks) * 512 + lane * 8]);
        o[ct] = __builtin_amdgcn_mfma_f32_32x32x16_bf16(va, pb, o[ct], 0, 0, 0);
      }
    }

    // epilogue: out[row][c] = o^T * linv + bp
    float* orow = outp + ((size_t)b * N + row) * 64;
#pragma unroll
    for (int ct = 0; ct < 2; ++ct) {
#pragma unroll
      for (int mm = 0; mm < 4; ++mm) {
        int c0 = ct * 32 + mm * 8 + hi * 4;
        float4 bpv = *reinterpret_cast<const float4*>(bp + c0);
        float4 r;
        r.x = o[ct][4 * mm + 0] * linv + bpv.x;
        r.y = o[ct][4 * mm + 1] * linv + bpv.y;
        r.z = o[ct][4 * mm + 2] * linv + bpv.z;
        r.w = o[ct][4 * mm + 3] * linv + bpv.w;
        *reinterpret_cast<float4*>(orow + c0) = r;
      }
    }
  }
}

// ---------------------------------------------------------------------------
extern "C" void kernel_launch(void* const* d_in, const int* in_sizes, int n_in,
                              void* d_out, int out_size, void* d_ws,
                              size_t ws_size, hipStream_t stream) {
  const float* x    = (const float*)d_in[0];
  const float* Wq   = (const float*)d_in[3];
  const float* bq   = (const float*)d_in[4];
  const float* Wkv  = (const float*)d_in[5];
  const float* bkv  = (const float*)d_in[6];
  const float* sr_w = (const float*)d_in[7];
  const float* sr_b = (const float*)d_in[8];
  const float* ln_g = (const float*)d_in[9];
  const float* ln_b = (const float*)d_in[10];
  const float* Wp   = (const float*)d_in[11];
  const float* bp   = (const float*)d_in[12];
  float* outp = (float*)d_out;

  // ws layout (2 MB): Wt region is reused by MTf/VpTf/sbf after conv.
  float* Wt  = (float*)d_ws;              // 1 MB (transpose_w -> conv_ln_kv)
  float* Kws = Wt + 262144;               // 512 KB
  float* Vws = Kws + 131072;              // 512 KB
  ushort_t* MTf  = (ushort_t*)d_ws;       // 256 KB (after conv, overwrites Wt)
  ushort_t* VpTf = MTf + 131072;          // 256 KB
  ushort_t* sbf  = VpTf + 131072;         // 4 KB

  transpose_w<<<1024, 256, 0, stream>>>(sr_w, Wt);
  conv_ln_kv<<<256, 256, 0, stream>>>(x, Wt, sr_b, ln_g, ln_b, Wkv, bkv, Kws, Vws);
  prep<<<64, 256, 0, stream>>>(Kws, Vws, Wq, bq, Wp, MTf, VpTf, sbf);
  attn_mfma<<<512, 256, 0, stream>>>(x, MTf, VpTf, sbf, bp, outp);
}

// Round 4
// 88.301 us; speedup vs baseline: 4.2851x; 1.5174x over previous
//
#include <hip/hip_runtime.h>
#include <hip/hip_bf16.h>
#include <math.h>

// B=8, N=16384 (H=W=128), C=64, heads=1, d=64, SR=8 -> Nk=256.
// S = X @ (Wq K^T)/8 + bq.K^T/8 ; P = softmax(S) ; out = P @ (V Wp) + bp
// R4: conv rewritten as MFMA GEMM, K reordered spatial-major (k = kj*64 + c)
// so x reads are whole 256B rows; ki(8)-split partials + small reduce kernel.

#define B 8
#define N 16384
#define C 64
#define NK 256
#define HW 128

typedef unsigned short ushort_t;
typedef unsigned int uint_t;
typedef __attribute__((ext_vector_type(8))) short short8v;
typedef __attribute__((ext_vector_type(16))) float f32x16;

static __device__ inline ushort_t f2bf(float f) {
  __hip_bfloat16 h = __float2bfloat16(f);
  return *reinterpret_cast<ushort_t*>(&h);
}
static __device__ inline uint_t pk2(float a, float b) {
  return (uint_t)f2bf(a) | ((uint_t)f2bf(b) << 16);
}
static __device__ inline short8v mk8(uint_t a, uint_t b, uint_t c, uint_t d) {
  union { int4 i; short8v s; } u;
  u.i = make_int4((int)a, (int)b, (int)c, (int)d);
  return u.s;
}
static __device__ inline float max16(const f32x16 v) {
  float a = fmaxf(fmaxf(fmaxf(v[0], v[1]), fmaxf(v[2], v[3])),
                  fmaxf(fmaxf(v[4], v[5]), fmaxf(v[6], v[7])));
  float b = fmaxf(fmaxf(fmaxf(v[8], v[9]), fmaxf(v[10], v[11])),
                  fmaxf(fmaxf(v[12], v[13]), fmaxf(v[14], v[15])));
  return fmaxf(a, b);
}
static __device__ inline float sum16(const f32x16 v) {
  float a = ((v[0] + v[1]) + (v[2] + v[3])) + ((v[4] + v[5]) + (v[6] + v[7]));
  float b = ((v[8] + v[9]) + (v[10] + v[11])) + ((v[12] + v[13]) + (v[14] + v[15]));
  return a + b;
}

// ---------------------------------------------------------------------------
// Kernel T: sr_w [o][c][ki][kj] -> bf16 fragment-linear weight blocks.
// K order: k = kj*64 + c (per ki slice of 512). A-frag (mfma_f32_32x32x16_bf16,
// A[m=o][k]): chunk (ki,oh) of 16384 ushorts; addr = kk*512 + l*8 + e with
// kk = kj*4 + (c>>4), l = ((c>>3)&1)*32 + (o&31), e = c&7.
__global__ __launch_bounds__(256) void transpose_w(const float* __restrict__ sr_w,
                                                   ushort_t* __restrict__ Wf) {
  int idx = blockIdx.x * 256 + threadIdx.x;   // 262144
  int o = idx >> 12;
  int r = idx & 4095;
  int c = r >> 6;
  int ki = (r >> 3) & 7;
  int kj = r & 7;
  int oh = o >> 5;
  int l = ((c >> 3) & 1) * 32 + (o & 31);
  int kk = kj * 4 + (c >> 4);
  int e = c & 7;
  Wf[(ki * 2 + oh) * 16384 + kk * 512 + l * 8 + e] = f2bf(sr_w[idx]);
}

// ---------------------------------------------------------------------------
// Kernel A: conv partial GEMM. Grid 512 = b(8) x pg(8) x ki(8); 128 thr
// (2 waves = oh). Wave: 32 patches x 32 outs, K=512 (kernel-row ki).
// No LDS. B-frags packed from global x rows; A-frags from Wf (L2-hot).
// Partials stored lane-linear: part[bi*2048 + oh*1024 + lane*16 + reg].
__global__ __launch_bounds__(128) void conv_mfma(
    const float* __restrict__ x, const ushort_t* __restrict__ Wf,
    float* __restrict__ part) {
  const int t = threadIdx.x;
  const int bi = blockIdx.x;
  const int b = bi >> 6;
  const int pg = (bi >> 3) & 7;
  const int ki = bi & 7;
  const int oh = t >> 6;
  const int lane = t & 63;
  const int lo5 = lane & 31;
  const int hi = lane >> 5;

  const int P = pg * 32 + lo5;            // patch in batch (0..255)
  const int prow = P >> 4, pcol = P & 15;
  const float* rowbase =
      x + ((size_t)b * N + (prow * 8 + ki) * HW + pcol * 8) * C;
  const ushort_t* wbase = Wf + (ki * 2 + oh) * 16384 + lane * 8;

  f32x16 acc;
#pragma unroll
  for (int r = 0; r < 16; ++r) acc[r] = 0.f;

#pragma unroll
  for (int kk = 0; kk < 32; ++kk) {
    const int kj = kk >> 2;
    const int c0 = (kk & 3) * 16 + hi * 8;
    const float4* xp = reinterpret_cast<const float4*>(rowbase + kj * C + c0);
    float4 f0 = xp[0];
    float4 f1 = xp[1];
    short8v bfr = mk8(pk2(f0.x, f0.y), pk2(f0.z, f0.w), pk2(f1.x, f1.y),
                      pk2(f1.z, f1.w));
    short8v afr = *reinterpret_cast<const short8v*>(wbase + kk * 512);
    acc = __builtin_amdgcn_mfma_f32_32x32x16_bf16(afr, bfr, acc, 0, 0, 0);
  }

  float* dst = part + (size_t)bi * 2048 + oh * 1024 + lane * 16;
#pragma unroll
  for (int q = 0; q < 4; ++q) {
    *reinterpret_cast<float4*>(dst + 4 * q) =
        make_float4(acc[4 * q + 0], acc[4 * q + 1], acc[4 * q + 2],
                    acc[4 * q + 3]);
  }
}

// ---------------------------------------------------------------------------
// Kernel S: reduce ki-partials + bias + LayerNorm + KV projection.
// Grid 64 = b(8) x pg(8); 256 thr. 32 patches per block.
__global__ __launch_bounds__(256) void sum_ln_kv(
    const float* __restrict__ part, const float* __restrict__ sr_b,
    const float* __restrict__ ln_g, const float* __restrict__ ln_b,
    const float* __restrict__ Wkv, const float* __restrict__ bkv,
    float* __restrict__ Kws, float* __restrict__ Vws) {
  __shared__ float convs[32 * 68];
  __shared__ float ns[32 * 64];

  const int t = threadIdx.x;
  const int b = blockIdx.x >> 3;
  const int pg = blockIdx.x & 7;
  {
    const int lane = t & 63;
    const int rhalf = (t >> 6) & 1;
    const int oh = t >> 7;
    float a[8];
#pragma unroll
    for (int r = 0; r < 8; ++r) a[r] = 0.f;
#pragma unroll
    for (int ki = 0; ki < 8; ++ki) {
      const float* src = part + ((size_t)(b * 64 + pg * 8 + ki)) * 2048 +
                         oh * 1024 + lane * 16 + rhalf * 8;
      float4 u0 = *reinterpret_cast<const float4*>(src + 0);
      float4 u1 = *reinterpret_cast<const float4*>(src + 4);
      a[0] += u0.x; a[1] += u0.y; a[2] += u0.z; a[3] += u0.w;
      a[4] += u1.x; a[5] += u1.y; a[6] += u1.z; a[7] += u1.w;
    }
    const int p = lane & 31;
#pragma unroll
    for (int r = 0; r < 8; ++r) {
      int reg = rhalf * 8 + r;
      int o = oh * 32 + (reg & 3) + 8 * (reg >> 2) + 4 * (lane >> 5);
      convs[p * 68 + o] = a[r] + sr_b[o];
    }
  }
  __syncthreads();
  // LayerNorm: wave w handles patches w*8..w*8+7; lane = channel
  {
    const int lane = t & 63;
    const int w = t >> 6;
    float g = ln_g[lane], bb = ln_b[lane];
#pragma unroll
    for (int rr = 0; rr < 8; ++rr) {
      int p = w * 8 + rr;
      float v = convs[p * 68 + lane];
      float s = v, s2 = v * v;
#pragma unroll
      for (int mask = 1; mask < 64; mask <<= 1) {
        s += __shfl_xor(s, mask, 64);
        s2 += __shfl_xor(s2, mask, 64);
      }
      float mu = s * (1.f / 64.f);
      float var = s2 * (1.f / 64.f) - mu * mu;
      ns[p * 64 + lane] = (v - mu) * rsqrtf(var + 1e-5f) * g + bb;
    }
  }
  __syncthreads();
  // KV projection: thread = (j in [0,128), rr0 in {0,1}); 16 rows each
  {
    const int j = t & 127;
    const int rr0 = t >> 7;
    float bj = bkv[j];
    float a[16];
#pragma unroll
    for (int i = 0; i < 16; ++i) a[i] = bj;
#pragma unroll 8
    for (int c = 0; c < 64; ++c) {
      float wv = Wkv[c * 128 + j];
#pragma unroll
      for (int i = 0; i < 16; ++i) a[i] += ns[(rr0 + 2 * i) * 64 + c] * wv;
    }
    float* dst = (j < 64) ? Kws : Vws;
    const int jj = j & 63;
    const size_t Pb = (size_t)b * NK + pg * 32;
#pragma unroll
    for (int i = 0; i < 16; ++i) dst[(Pb + rr0 + 2 * i) * 64 + jj] = a[i];
  }
}

// ---------------------------------------------------------------------------
// Kernel P: per-batch operand prep (unchanged from R3).
__global__ __launch_bounds__(256) void prep(
    const float* __restrict__ Kws, const float* __restrict__ Vws,
    const float* __restrict__ Wq, const float* __restrict__ bq,
    const float* __restrict__ Wp, ushort_t* __restrict__ MTf,
    ushort_t* __restrict__ VpTf, ushort_t* __restrict__ sbf) {
  __shared__ float sA[64 * 65];
  __shared__ float sBv[64 * 257];
  const int t = threadIdx.x;
  const int b = blockIdx.x >> 3;
  const int p = blockIdx.x & 7;
  const float SC = 0.125f * 1.4426950408889634f;

  if (p < 4) {
#pragma unroll
    for (int i = 0; i < 16; ++i) {
      int o = t + 256 * i;
      sA[(o & 63) * 65 + (o >> 6)] = Wq[o];   // sA[d][c] = Wq[c][d]
    }
    {
      const float4* k4 =
          reinterpret_cast<const float4*>(Kws + ((size_t)b * NK + p * 64) * 64);
      float4* b4 = reinterpret_cast<float4*>(sBv);
#pragma unroll
      for (int i = 0; i < 4; ++i) b4[t + 256 * i] = k4[t + 256 * i];
    }
    __syncthreads();
    const int c = t & 63;
    const int jbase = t >> 6;
    float wcol[64];
#pragma unroll
    for (int d = 0; d < 64; ++d) wcol[d] = sA[d * 65 + c];
    const int ks = c >> 4;
    const int lpart = ((c >> 3) & 1) * 32;
    const int e = c & 7;
#pragma unroll 4
    for (int u = 0; u < 16; ++u) {
      int jl = jbase + 4 * u;
      float s = 0.f;
#pragma unroll
      for (int d = 0; d < 64; ++d) s += sBv[jl * 64 + d] * wcol[d];
      int j = p * 64 + jl;
      int kt = j >> 5;
      int l = lpart + (j & 31);
      MTf[(size_t)b * 16384 + (kt * 4 + ks) * 512 + l * 8 + e] = f2bf(s * SC);
    }
    if (t < 64) {
      float s = 0.f;
      for (int d = 0; d < 64; ++d) s += bq[d] * sBv[t * 64 + d];
      sbf[b * NK + p * 64 + t] = f2bf(s * SC);
    }
  } else {
    const int pc = p - 4;
#pragma unroll
    for (int i = 0; i < 16; ++i) {
      int o = t + 256 * i;
      sA[(o >> 6) * 65 + (o & 63)] = Wp[o];   // sA[d][c] = Wp[d][c]
    }
    {
      const float* Vb = Vws + (size_t)b * NK * 64;
#pragma unroll
      for (int i = 0; i < 64; ++i) {
        int o = t + 256 * i;
        sBv[(o & 63) * 257 + (o >> 6)] = Vb[o];  // sBv[d][j] = V[j][d]
      }
    }
    __syncthreads();
    const int j = t;
    float vrow[64];
#pragma unroll
    for (int d = 0; d < 64; ++d) vrow[d] = sBv[d * 257 + j];
    const int ks = j >> 4;
    const int lpart = ((j >> 3) & 1) * 32;
    const int e = j & 7;
#pragma unroll 4
    for (int u = 0; u < 16; ++u) {
      int c = pc * 16 + u;
      float s = 0.f;
#pragma unroll
      for (int d = 0; d < 64; ++d) s += vrow[d] * sA[d * 65 + c];
      int ct = c >> 5;
      int l = lpart + (c & 31);
      VpTf[(size_t)b * 16384 + (ct * 16 + ks) * 512 + l * 8 + e] = f2bf(s);
    }
  }
}

// ---------------------------------------------------------------------------
// Kernel B: MFMA attention (unchanged from R3).
__global__ __launch_bounds__(256, 2) void attn_mfma(
    const float* __restrict__ x, const ushort_t* __restrict__ MTf,
    const ushort_t* __restrict__ VpTf, const ushort_t* __restrict__ sbf,
    const float* __restrict__ bp, float* __restrict__ outp) {
  __shared__ ushort_t sMT[16384];
  __shared__ ushort_t sVT[16384];
  __shared__ ushort_t sSB[256];

  const int t = threadIdx.x;
  const int b = blockIdx.x >> 6;
  const int rb = blockIdx.x & 63;
  const int wave = t >> 6;
  const int lane = t & 63;
  const int lo5 = lane & 31;
  const int hi = lane >> 5;

  {
    const uint4* gm = reinterpret_cast<const uint4*>(MTf + (size_t)b * 16384);
    const uint4* gv = reinterpret_cast<const uint4*>(VpTf + (size_t)b * 16384);
    uint4* dm = reinterpret_cast<uint4*>(sMT);
    uint4* dv = reinterpret_cast<uint4*>(sVT);
#pragma unroll
    for (int i = 0; i < 8; ++i) {
      dm[t + i * 256] = gm[t + i * 256];
      dv[t + i * 256] = gv[t + i * 256];
    }
    if (t < 32)
      reinterpret_cast<uint4*>(sSB)[t] =
          reinterpret_cast<const uint4*>(sbf + b * NK)[t];
  }
  __syncthreads();

  for (int t2 = 0; t2 < 2; ++t2) {
    const int row = rb * 256 + wave * 64 + t2 * 32 + lo5;
    const float* xrow = x + ((size_t)b * N + row) * 64;
    const float4* xp = reinterpret_cast<const float4*>(xrow);

    short8v bx[4];
#pragma unroll
    for (int ks = 0; ks < 4; ++ks) {
      float4 f0 = xp[ks * 4 + hi * 2 + 0];
      float4 f1 = xp[ks * 4 + hi * 2 + 1];
      bx[ks] = mk8(pk2(f0.x, f0.y), pk2(f0.z, f0.w), pk2(f1.x, f1.y),
                   pk2(f1.z, f1.w));
    }

    f32x16 acc[8];
#pragma unroll
    for (int kt = 0; kt < 8; ++kt)
#pragma unroll
      for (int r = 0; r < 16; ++r) acc[kt][r] = 0.f;

#pragma unroll
    for (int kt = 0; kt < 8; ++kt) {
#pragma unroll
      for (int ks = 0; ks < 4; ++ks) {
        const short8v a =
            *reinterpret_cast<const short8v*>(&sMT[(kt * 4 + ks) * 512 + lane * 8]);
        acc[kt] = __builtin_amdgcn_mfma_f32_32x32x16_bf16(a, bx[ks], acc[kt], 0, 0, 0);
      }
      ushort_t sv = sSB[kt * 32 + lo5];
      short8v a5 = mk8(hi ? 0u : (uint_t)sv, 0u, 0u, 0u);
      short8v b5 = mk8(hi ? 0u : 0x3F80u, 0u, 0u, 0u);
      acc[kt] = __builtin_amdgcn_mfma_f32_32x32x16_bf16(a5, b5, acc[kt], 0, 0, 0);
    }

    float mx = max16(acc[0]);
#pragma unroll
    for (int kt = 1; kt < 8; ++kt) mx = fmaxf(mx, max16(acc[kt]));
    mx = fmaxf(mx, __shfl_xor(mx, 32, 64));
    float sum = 0.f;
#pragma unroll
    for (int kt = 0; kt < 8; ++kt) {
#pragma unroll
      for (int r = 0; r < 16; ++r) acc[kt][r] = exp2f(acc[kt][r] - mx);
      sum += sum16(acc[kt]);
    }
    sum += __shfl_xor(sum, 32, 64);
    const float linv = 1.f / sum;

    f32x16 o[2];
#pragma unroll
    for (int ct = 0; ct < 2; ++ct)
#pragma unroll
      for (int r = 0; r < 16; ++r) o[ct][r] = 0.f;

#pragma unroll
    for (int ks = 0; ks < 16; ++ks) {
      const int kt = ks >> 1;
      const int m0 = (ks & 1) * 2;
      uint_t Aw = pk2(acc[kt][4 * m0 + 0], acc[kt][4 * m0 + 1]);
      uint_t Bw = pk2(acc[kt][4 * m0 + 2], acc[kt][4 * m0 + 3]);
      uint_t Cw = pk2(acc[kt][4 * m0 + 4], acc[kt][4 * m0 + 5]);
      uint_t Dw = pk2(acc[kt][4 * m0 + 6], acc[kt][4 * m0 + 7]);
      asm volatile("v_permlane32_swap_b32 %0, %1" : "+v"(Aw), "+v"(Cw));
      asm volatile("v_permlane32_swap_b32 %0, %1" : "+v"(Bw), "+v"(Dw));
      const short8v pb = mk8(Aw, Bw, Cw, Dw);
#pragma unroll
      for (int ct = 0; ct < 2; ++ct) {
        const short8v va =
            *reinterpret_cast<const short8v*>(&sVT[(ct * 16 + ks) * 512 + lane * 8]);
        o[ct] = __builtin_amdgcn_mfma_f32_32x32x16_bf16(va, pb, o[ct], 0, 0, 0);
      }
    }

    float* orow = outp + ((size_t)b * N + row) * 64;
#pragma unroll
    for (int ct = 0; ct < 2; ++ct) {
#pragma unroll
      for (int mm = 0; mm < 4; ++mm) {
        int c0 = ct * 32 + mm * 8 + hi * 4;
        float4 bpv = *reinterpret_cast<const float4*>(bp + c0);
        float4 r;
        r.x = o[ct][4 * mm + 0] * linv + bpv.x;
        r.y = o[ct][4 * mm + 1] * linv + bpv.y;
        r.z = o[ct][4 * mm + 2] * linv + bpv.z;
        r.w = o[ct][4 * mm + 3] * linv + bpv.w;
        *reinterpret_cast<float4*>(orow + c0) = r;
      }
    }
  }
}

// ---------------------------------------------------------------------------
extern "C" void kernel_launch(void* const* d_in, const int* in_sizes, int n_in,
                              void* d_out, int out_size, void* d_ws,
                              size_t ws_size, hipStream_t stream) {
  const float* x    = (const float*)d_in[0];
  const float* Wq   = (const float*)d_in[3];
  const float* bq   = (const float*)d_in[4];
  const float* Wkv  = (const float*)d_in[5];
  const float* bkv  = (const float*)d_in[6];
  const float* sr_w = (const float*)d_in[7];
  const float* sr_b = (const float*)d_in[8];
  const float* ln_g = (const float*)d_in[9];
  const float* ln_b = (const float*)d_in[10];
  const float* Wp   = (const float*)d_in[11];
  const float* bp   = (const float*)d_in[12];
  float* outp = (float*)d_out;

  char* ws = (char*)d_ws;
  // [0, 512K)   Wf   bf16 fragment weights (transpose_w -> conv_mfma)
  // [512K, 1M)  Kws  fp32
  // [1M, 1.5M)  Vws  fp32
  // [1.5M, 5.5M) part fp32 (conv -> sum); overlaid afterwards by:
  // [1.5M, 1.75M) MTf, [1.75M, 2M) VpTf, [2M, +4K) sbf   (prep -> attn)
  ushort_t* Wf   = (ushort_t*)(ws);
  float*    Kws  = (float*)(ws + (512 << 10));
  float*    Vws  = (float*)(ws + (1024 << 10));
  float*    part = (float*)(ws + (1536 << 10));
  ushort_t* MTf  = (ushort_t*)(ws + (1536 << 10));
  ushort_t* VpTf = (ushort_t*)(ws + (1792 << 10));
  ushort_t* sbf  = (ushort_t*)(ws + (2048 << 10));

  transpose_w<<<1024, 256, 0, stream>>>(sr_w, Wf);
  conv_mfma<<<512, 128, 0, stream>>>(x, Wf, part);
  sum_ln_kv<<<64, 256, 0, stream>>>(part, sr_b, ln_g, ln_b, Wkv, bkv, Kws, Vws);
  prep<<<64, 256, 0, stream>>>(Kws, Vws, Wq, bq, Wp, MTf, VpTf, sbf);
  attn_mfma<<<512, 256, 0, stream>>>(x, MTf, VpTf, sbf, bp, outp);
}